// Round 1
// baseline (553.693 us; speedup 1.0000x reference)
//
#include <hip/hip_runtime.h>

#define N_NODES 50000
#define N_EDGES 800000
#define ETOT    (N_EDGES + N_NODES)   // 850000 with self loops
#define IN_DIM  128
#define HID     64
#define HID2    32
#define HEADS   4
#define LATENT  32
#define NEG_SLOPE 0.2f

// ---------------- workspace layout (float offsets) ----------------
// xh1 occupies [0, 12.8M). Layer-2 buffers overlay it once xh1 is dead.
#define OFF_XH1   ((size_t)0)            // 50000*256 = 12,800,000
#define OFF_XH2   ((size_t)0)            // 50000*128 =  6,400,000 (overlay)
#define OFF_ALS2  ((size_t)6400000)      // 200,000
#define OFF_ALD2  ((size_t)6600000)      // 200,000
#define OFF_DEN2  ((size_t)6800000)      // 200,000   \ contiguous zero region 2
#define OFF_AGG2  ((size_t)7000000)      // 1,600,000 /
#define OFF_ALS1  ((size_t)12800000)     // 200,000
#define OFF_ALD1  ((size_t)13000000)     // 200,000
#define OFF_DEN1  ((size_t)13200000)     // 200,000   \ contiguous zero region 1
#define OFF_AGG1  ((size_t)13400000)     // 3,200,000 /
// total 16,600,000 floats = 66.4 MB

__device__ __forceinline__ float lrelu(float v) {
    return v > 0.f ? v : NEG_SLOPE * v;
}

// K1: xh1 = x @ W1  [50000,256]; als1/ald1 [50000,4] via wave reduction.
#define NPB1 8
__global__ void k_gemm1(const float* __restrict__ x, const float* __restrict__ W1,
                        const float* __restrict__ as1, const float* __restrict__ ad1,
                        float* __restrict__ xh1, float* __restrict__ als,
                        float* __restrict__ ald) {
    __shared__ float xs[NPB1][IN_DIM];
    const int tid = threadIdx.x;              // 256
    const int n0  = blockIdx.x * NPB1;
    for (int i = tid; i < NPB1 * IN_DIM; i += 256) {
        int ni = i >> 7, ci = i & 127;
        xs[ni][ci] = x[(size_t)(n0 + ni) * IN_DIM + ci];
    }
    __syncthreads();
    float acc[NPB1];
#pragma unroll
    for (int i = 0; i < NPB1; i++) acc[i] = 0.f;
    for (int k = 0; k < IN_DIM; k++) {
        float w = W1[k * (HEADS * HID) + tid];
#pragma unroll
        for (int i = 0; i < NPB1; i++) acc[i] += xs[i][k] * w;
    }
    const int h = tid >> 6, c = tid & 63;     // wave == one head
    const float asv = as1[h * HID + c], adv = ad1[h * HID + c];
#pragma unroll
    for (int i = 0; i < NPB1; i++) {
        const int n = n0 + i;
        xh1[(size_t)n * (HEADS * HID) + tid] = acc[i];
        float ps = acc[i] * asv, pd = acc[i] * adv;
        for (int off = 32; off; off >>= 1) {
            ps += __shfl_down(ps, off);
            pd += __shfl_down(pd, off);
        }
        if (c == 0) { als[n * HEADS + h] = ps; ald[n * HEADS + h] = pd; }
    }
}

// K2/K6: denom[dst,h] += exp(leaky_relu(al_s[src,h]+al_d[dst,h]))
template <int HC>  // unused dim marker; same code both layers
__global__ void k_denom(const int* __restrict__ ei, const float* __restrict__ als,
                        const float* __restrict__ ald, float* __restrict__ denom) {
    const int t = blockIdx.x * blockDim.x + threadIdx.x;
    if (t >= ETOT * HEADS) return;
    const int e = t >> 2, h = t & 3;
    int src, dst;
    if (e < N_EDGES) { src = ei[e]; dst = ei[N_EDGES + e]; }
    else             { src = dst = e - N_EDGES; }
    const float a = lrelu(als[src * HEADS + h] + ald[dst * HEADS + h]);
    atomicAdd(&denom[dst * HEADS + h], expf(a));
}

// K3: layer-1 aggregation. One 64-lane wave per edge, lane = channel.
__global__ void k_agg1(const int* __restrict__ ei, const float* __restrict__ als,
                       const float* __restrict__ ald, const float* __restrict__ denom,
                       const float* __restrict__ xh1, float* __restrict__ agg1) {
    const int wave = (blockIdx.x * blockDim.x + threadIdx.x) >> 6;
    const int lane = threadIdx.x & 63;
    if (wave >= ETOT) return;
    int src, dst;
    if (wave < N_EDGES) { src = ei[wave]; dst = ei[N_EDGES + wave]; }
    else                { src = dst = wave - N_EDGES; }
    float v = 0.f;
    if (lane < HEADS) {
        const float a = lrelu(als[src * HEADS + lane] + ald[dst * HEADS + lane]);
        v = expf(a) / (denom[dst * HEADS + lane] + 1e-16f);
    }
    const float c0 = __shfl(v, 0), c1 = __shfl(v, 1),
                c2 = __shfl(v, 2), c3 = __shfl(v, 3);
    const float* xp = xh1 + (size_t)src * (HEADS * HID);
    const float m = xp[lane] * c0 + xp[64 + lane] * c1 +
                    xp[128 + lane] * c2 + xp[192 + lane] * c3;
    atomicAdd(&agg1[(size_t)dst * HID + lane], 0.25f * m);
}

// K5: h1 = relu(agg1 + b1); xh2 = h1 @ W2 [50000,128]; als2/ald2.
#define NPB2 8
__global__ void k_gemm2(const float* __restrict__ agg1, const float* __restrict__ b1,
                        const float* __restrict__ W2, const float* __restrict__ as2,
                        const float* __restrict__ ad2, float* __restrict__ xh2,
                        float* __restrict__ als, float* __restrict__ ald) {
    __shared__ float hs[NPB2][HID];
    const int tid = threadIdx.x;              // 128
    const int n0  = blockIdx.x * NPB2;
    for (int i = tid; i < NPB2 * HID; i += 128) {
        int ni = i >> 6, ci = i & 63;
        float v = agg1[(size_t)(n0 + ni) * HID + ci] + b1[ci];
        hs[ni][ci] = v > 0.f ? v : 0.f;
    }
    __syncthreads();
    float acc[NPB2];
#pragma unroll
    for (int i = 0; i < NPB2; i++) acc[i] = 0.f;
    for (int k = 0; k < HID; k++) {
        float w = W2[k * (HEADS * HID2) + tid];
#pragma unroll
        for (int i = 0; i < NPB2; i++) acc[i] += hs[i][k] * w;
    }
    const int h = tid >> 5, c = tid & 31;     // 32-lane group == one head
    const float asv = as2[h * HID2 + c], adv = ad2[h * HID2 + c];
#pragma unroll
    for (int i = 0; i < NPB2; i++) {
        const int n = n0 + i;
        xh2[(size_t)n * (HEADS * HID2) + tid] = acc[i];
        float ps = acc[i] * asv, pd = acc[i] * adv;
        for (int off = 16; off; off >>= 1) {
            ps += __shfl_down(ps, off, 32);
            pd += __shfl_down(pd, off, 32);
        }
        if (c == 0) { als[n * HEADS + h] = ps; ald[n * HEADS + h] = pd; }
    }
}

// K7: layer-2 aggregation. 32 lanes per edge.
__global__ void k_agg2(const int* __restrict__ ei, const float* __restrict__ als,
                       const float* __restrict__ ald, const float* __restrict__ denom,
                       const float* __restrict__ xh2, float* __restrict__ agg2) {
    const int t = blockIdx.x * blockDim.x + threadIdx.x;
    const int e = t >> 5;
    const int lane = threadIdx.x & 31;
    if (e >= ETOT) return;
    int src, dst;
    if (e < N_EDGES) { src = ei[e]; dst = ei[N_EDGES + e]; }
    else             { src = dst = e - N_EDGES; }
    float v = 0.f;
    if (lane < HEADS) {
        const float a = lrelu(als[src * HEADS + lane] + ald[dst * HEADS + lane]);
        v = expf(a) / (denom[dst * HEADS + lane] + 1e-16f);
    }
    const float c0 = __shfl(v, 0, 32), c1 = __shfl(v, 1, 32),
                c2 = __shfl(v, 2, 32), c3 = __shfl(v, 3, 32);
    const float* xp = xh2 + (size_t)src * (HEADS * HID2);
    const float m = xp[lane] * c0 + xp[32 + lane] * c1 +
                    xp[64 + lane] * c2 + xp[96 + lane] * c3;
    atomicAdd(&agg2[(size_t)dst * HID2 + lane], 0.25f * m);
}

// K8: h2 = relu(agg2 + b2); mu = h2@W_mu + b_mu; logvar = h2@W_lv + b_lv.
#define NPB3 4
__global__ void k_final(const float* __restrict__ agg2, const float* __restrict__ b2,
                        const float* __restrict__ Wmu, const float* __restrict__ bmu,
                        const float* __restrict__ Wlv, const float* __restrict__ blv,
                        float* __restrict__ out) {
    __shared__ float hs[NPB3][HID2];
    const int tid = threadIdx.x;              // 256
    const int n0  = blockIdx.x * NPB3;
    if (tid < NPB3 * HID2) {
        int ni = tid >> 5, ci = tid & 31;
        float v = agg2[(size_t)(n0 + ni) * HID2 + ci] + b2[ci];
        hs[ni][ci] = v > 0.f ? v : 0.f;
    }
    __syncthreads();
    const int ni = tid >> 6;                  // 4 nodes per block
    const int which = (tid >> 5) & 1;         // 0 = mu, 1 = logvar
    const int l = tid & 31;
    const float* W = which ? Wlv : Wmu;
    const float* b = which ? blv : bmu;
    float acc = b[l];
#pragma unroll
    for (int c = 0; c < HID2; c++) acc += hs[ni][c] * W[c * LATENT + l];
    const int n = n0 + ni;
    out[(size_t)which * N_NODES * LATENT + (size_t)n * LATENT + l] = acc;
}

extern "C" void kernel_launch(void* const* d_in, const int* in_sizes, int n_in,
                              void* d_out, int out_size, void* d_ws, size_t ws_size,
                              hipStream_t stream) {
    const float* x    = (const float*)d_in[0];
    const int*   ei   = (const int*)d_in[1];
    const float* W1   = (const float*)d_in[2];
    const float* as1  = (const float*)d_in[3];
    const float* ad1  = (const float*)d_in[4];
    const float* b1   = (const float*)d_in[5];
    const float* W2   = (const float*)d_in[6];
    const float* as2  = (const float*)d_in[7];
    const float* ad2  = (const float*)d_in[8];
    const float* b2   = (const float*)d_in[9];
    const float* Wmu  = (const float*)d_in[10];
    const float* bmu  = (const float*)d_in[11];
    const float* Wlv  = (const float*)d_in[12];
    const float* blv  = (const float*)d_in[13];
    float* out = (float*)d_out;
    float* ws  = (float*)d_ws;

    float* xh1  = ws + OFF_XH1;
    float* als1 = ws + OFF_ALS1;
    float* ald1 = ws + OFF_ALD1;
    float* den1 = ws + OFF_DEN1;
    float* agg1 = ws + OFF_AGG1;
    float* xh2  = ws + OFF_XH2;
    float* als2 = ws + OFF_ALS2;
    float* ald2 = ws + OFF_ALD2;
    float* den2 = ws + OFF_DEN2;
    float* agg2 = ws + OFF_AGG2;

    // zero region 1 (den1 + agg1, contiguous)
    hipMemsetAsync(den1, 0, (size_t)(200000 + 3200000) * sizeof(float), stream);

    k_gemm1<<<N_NODES / NPB1, 256, 0, stream>>>(x, W1, as1, ad1, xh1, als1, ald1);

    {
        int total = ETOT * HEADS;
        k_denom<HID><<<(total + 255) / 256, 256, 0, stream>>>(ei, als1, ald1, den1);
    }
    k_agg1<<<(ETOT + 3) / 4, 256, 0, stream>>>(ei, als1, ald1, den1, xh1, agg1);

    // zero region 2 (den2 + agg2, contiguous) — after K3 (overlays dead xh1)
    hipMemsetAsync(den2, 0, (size_t)(200000 + 1600000) * sizeof(float), stream);

    k_gemm2<<<N_NODES / NPB2, 128, 0, stream>>>(agg1, b1, W2, as2, ad2, xh2, als2, ald2);

    {
        int total = ETOT * HEADS;
        k_denom<HID2><<<(total + 255) / 256, 256, 0, stream>>>(ei, als2, ald2, den2);
    }
    {
        int total = ETOT * 32;
        k_agg2<<<(total + 255) / 256, 256, 0, stream>>>(ei, als2, ald2, den2, xh2, agg2);
    }

    k_final<<<N_NODES / NPB3, 256, 0, stream>>>(agg2, b2, Wmu, bmu, Wlv, blv, out);
}

// Round 2
// 440.915 us; speedup vs baseline: 1.2558x; 1.2558x over previous
//
#include <hip/hip_runtime.h>

#define N_NODES 50000
#define N_EDGES 800000
#define IN_DIM  128
#define HID     64
#define HID2    32
#define HEADS   4
#define LATENT  32
#define NEG_SLOPE 0.2f

// ---------------- workspace layout (float offsets) ----------------
// Phase A: xh1 [0,12.8M). Phase B overlays it: xh2/agg2/als2/ald2.
#define OFF_XH1   ((size_t)0)            // 12,800,000
#define OFF_XH2   ((size_t)0)            //  6,400,000 (overlay, xh1 dead)
#define OFF_AGG2  ((size_t)6400000)      //  1,600,000
#define OFF_ALS2  ((size_t)8000000)      //    200,000
#define OFF_ALD2  ((size_t)8200000)      //    200,000
#define OFF_AGG1  ((size_t)12800000)     //  3,200,000
#define OFF_ALS1  ((size_t)16000000)     //    200,000
#define OFF_ALD1  ((size_t)16200000)     //    200,000
// CSR (ints, stored in float slots)
#define OFF_DEG   ((size_t)16400000)     //     50,000  (reused as scatter cursor)
#define OFF_ROW   ((size_t)16450000)     //     50,001
#define OFF_BSUM  ((size_t)16500004)     //        256
#define OFF_ESRC  ((size_t)16500260)     //    800,000
// total 17,300,260 floats = 69.2 MB

#define NB_SCAN ((N_NODES + 255) / 256)  // 196

__device__ __forceinline__ float lrelu(float v) {
    return v > 0.f ? v : NEG_SLOPE * v;
}

// ---------------- K1: xh1 = x @ W1 ; als1/ald1 ----------------
#define NPB1 8
__global__ void k_gemm1(const float* __restrict__ x, const float* __restrict__ W1,
                        const float* __restrict__ as1, const float* __restrict__ ad1,
                        float* __restrict__ xh1, float* __restrict__ als,
                        float* __restrict__ ald) {
    __shared__ float xs[NPB1][IN_DIM];
    const int tid = threadIdx.x;              // 256
    const int n0  = blockIdx.x * NPB1;
    for (int i = tid; i < NPB1 * IN_DIM; i += 256) {
        int ni = i >> 7, ci = i & 127;
        xs[ni][ci] = x[(size_t)(n0 + ni) * IN_DIM + ci];
    }
    __syncthreads();
    float acc[NPB1];
#pragma unroll
    for (int i = 0; i < NPB1; i++) acc[i] = 0.f;
    for (int k = 0; k < IN_DIM; k++) {
        float w = W1[k * (HEADS * HID) + tid];
#pragma unroll
        for (int i = 0; i < NPB1; i++) acc[i] += xs[i][k] * w;
    }
    const int h = tid >> 6, c = tid & 63;     // wave == one head
    const float asv = as1[h * HID + c], adv = ad1[h * HID + c];
#pragma unroll
    for (int i = 0; i < NPB1; i++) {
        const int n = n0 + i;
        xh1[(size_t)n * (HEADS * HID) + tid] = acc[i];
        float ps = acc[i] * asv, pd = acc[i] * adv;
        for (int off = 32; off; off >>= 1) {
            ps += __shfl_down(ps, off);
            pd += __shfl_down(pd, off);
        }
        if (c == 0) { als[n * HEADS + h] = ps; ald[n * HEADS + h] = pd; }
    }
}

// ---------------- CSR build ----------------
__global__ void k_hist(const int* __restrict__ ei, int* __restrict__ deg) {
    const int e = blockIdx.x * blockDim.x + threadIdx.x;
    if (e >= N_EDGES) return;
    atomicAdd(&deg[ei[N_EDGES + e]], 1);
}

__global__ void k_scan_part(const int* __restrict__ deg, int* __restrict__ row,
                            int* __restrict__ bsum) {
    __shared__ int sm[256];
    const int tid = threadIdx.x;
    const int i = blockIdx.x * 256 + tid;
    const int v = (i < N_NODES) ? deg[i] : 0;
    sm[tid] = v;
    __syncthreads();
    for (int off = 1; off < 256; off <<= 1) {
        int t = (tid >= off) ? sm[tid - off] : 0;
        __syncthreads();
        sm[tid] += t;
        __syncthreads();
    }
    if (i < N_NODES) row[i] = sm[tid] - v;      // within-block exclusive
    if (tid == 255) bsum[blockIdx.x] = sm[255];
}

__global__ void k_scan_block(int* __restrict__ bsum) {
    __shared__ int sm[256];
    const int tid = threadIdx.x;
    const int v = (tid < NB_SCAN) ? bsum[tid] : 0;
    sm[tid] = v;
    __syncthreads();
    for (int off = 1; off < 256; off <<= 1) {
        int t = (tid >= off) ? sm[tid - off] : 0;
        __syncthreads();
        sm[tid] += t;
        __syncthreads();
    }
    if (tid < NB_SCAN) bsum[tid] = sm[tid] - v; // exclusive block offsets
}

__global__ void k_scan_add(int* __restrict__ row, const int* __restrict__ bsum,
                           int* __restrict__ cur) {
    const int i = blockIdx.x * 256 + threadIdx.x;
    if (i == 0) row[N_NODES] = N_EDGES;
    if (i >= N_NODES) return;
    const int r = row[i] + bsum[blockIdx.x];
    row[i] = r;
    cur[i] = r;
}

__global__ void k_scatter(const int* __restrict__ ei, int* __restrict__ cur,
                          int* __restrict__ esrc) {
    const int e = blockIdx.x * blockDim.x + threadIdx.x;
    if (e >= N_EDGES) return;
    const int s = ei[e], d = ei[N_EDGES + e];
    const int pos = atomicAdd(&cur[d], 1);
    esrc[pos] = s;
}

// ---------------- K3: layer-1 aggregation, CSR, one wave per node ----------------
__global__ void k_agg1_csr(const int* __restrict__ row, const int* __restrict__ esrc,
                           const float* __restrict__ als, const float* __restrict__ ald,
                           const float* __restrict__ xh1, float* __restrict__ agg1) {
    const int d = blockIdx.x * 4 + (threadIdx.x >> 6);
    const int c = threadIdx.x & 63;
    if (d >= N_NODES) return;
    const float4 ad4 = *(const float4*)(ald + (size_t)d * 4);
    // self loop init
    float den0, den1, den2, den3, num0, num1, num2, num3;
    {
        const float4 a4 = *(const float4*)(als + (size_t)d * 4);
        den0 = expf(lrelu(a4.x + ad4.x));
        den1 = expf(lrelu(a4.y + ad4.y));
        den2 = expf(lrelu(a4.z + ad4.z));
        den3 = expf(lrelu(a4.w + ad4.w));
        const float* p = xh1 + (size_t)d * 256 + c;
        num0 = den0 * p[0];  num1 = den1 * p[64];
        num2 = den2 * p[128]; num3 = den3 * p[192];
    }
    const int start = row[d], end = row[d + 1];
    int i = start;
    for (; i + 1 < end; i += 2) {
        const int s0 = esrc[i], s1 = esrc[i + 1];
        const float4 a0 = *(const float4*)(als + (size_t)s0 * 4);
        const float4 a1 = *(const float4*)(als + (size_t)s1 * 4);
        const float* p0 = xh1 + (size_t)s0 * 256 + c;
        const float* p1 = xh1 + (size_t)s1 * 256 + c;
        const float x00 = p0[0], x01 = p0[64], x02 = p0[128], x03 = p0[192];
        const float x10 = p1[0], x11 = p1[64], x12 = p1[128], x13 = p1[192];
        const float e00 = expf(lrelu(a0.x + ad4.x));
        const float e01 = expf(lrelu(a0.y + ad4.y));
        const float e02 = expf(lrelu(a0.z + ad4.z));
        const float e03 = expf(lrelu(a0.w + ad4.w));
        const float e10 = expf(lrelu(a1.x + ad4.x));
        const float e11 = expf(lrelu(a1.y + ad4.y));
        const float e12 = expf(lrelu(a1.z + ad4.z));
        const float e13 = expf(lrelu(a1.w + ad4.w));
        den0 += e00 + e10; den1 += e01 + e11;
        den2 += e02 + e12; den3 += e03 + e13;
        num0 += e00 * x00 + e10 * x10;
        num1 += e01 * x01 + e11 * x11;
        num2 += e02 * x02 + e12 * x12;
        num3 += e03 * x03 + e13 * x13;
    }
    if (i < end) {
        const int s0 = esrc[i];
        const float4 a0 = *(const float4*)(als + (size_t)s0 * 4);
        const float* p0 = xh1 + (size_t)s0 * 256 + c;
        const float e00 = expf(lrelu(a0.x + ad4.x));
        const float e01 = expf(lrelu(a0.y + ad4.y));
        const float e02 = expf(lrelu(a0.z + ad4.z));
        const float e03 = expf(lrelu(a0.w + ad4.w));
        den0 += e00; den1 += e01; den2 += e02; den3 += e03;
        num0 += e00 * p0[0];  num1 += e01 * p0[64];
        num2 += e02 * p0[128]; num3 += e03 * p0[192];
    }
    agg1[(size_t)d * HID + c] =
        0.25f * (num0 / den0 + num1 / den1 + num2 / den2 + num3 / den3);
}

// ---------------- K5: h1 = relu(agg1+b1); xh2 = h1 @ W2 ; als2/ald2 ----------------
#define NPB2 8
__global__ void k_gemm2(const float* __restrict__ agg1, const float* __restrict__ b1,
                        const float* __restrict__ W2, const float* __restrict__ as2,
                        const float* __restrict__ ad2, float* __restrict__ xh2,
                        float* __restrict__ als, float* __restrict__ ald) {
    __shared__ float hs[NPB2][HID];
    const int tid = threadIdx.x;              // 128
    const int n0  = blockIdx.x * NPB2;
    for (int i = tid; i < NPB2 * HID; i += 128) {
        int ni = i >> 6, ci = i & 63;
        float v = agg1[(size_t)(n0 + ni) * HID + ci] + b1[ci];
        hs[ni][ci] = v > 0.f ? v : 0.f;
    }
    __syncthreads();
    float acc[NPB2];
#pragma unroll
    for (int i = 0; i < NPB2; i++) acc[i] = 0.f;
    for (int k = 0; k < HID; k++) {
        float w = W2[k * (HEADS * HID2) + tid];
#pragma unroll
        for (int i = 0; i < NPB2; i++) acc[i] += hs[i][k] * w;
    }
    const int h = tid >> 5, c = tid & 31;     // 32-lane group == one head
    const float asv = as2[h * HID2 + c], adv = ad2[h * HID2 + c];
#pragma unroll
    for (int i = 0; i < NPB2; i++) {
        const int n = n0 + i;
        xh2[(size_t)n * (HEADS * HID2) + tid] = acc[i];
        float ps = acc[i] * asv, pd = acc[i] * adv;
        for (int off = 16; off; off >>= 1) {
            ps += __shfl_down(ps, off, 32);
            pd += __shfl_down(pd, off, 32);
        }
        if (c == 0) { als[n * HEADS + h] = ps; ald[n * HEADS + h] = pd; }
    }
}

// ---------------- K7: layer-2 aggregation, CSR, 2 edges per wave ----------------
__global__ void k_agg2_csr(const int* __restrict__ row, const int* __restrict__ esrc,
                           const float* __restrict__ als, const float* __restrict__ ald,
                           const float* __restrict__ xh2, float* __restrict__ agg2) {
    const int d = blockIdx.x * 4 + (threadIdx.x >> 6);
    const int lane = threadIdx.x & 63;
    const int c = lane & 31, half = lane >> 5;
    if (d >= N_NODES) return;
    const float4 ad4 = *(const float4*)(ald + (size_t)d * 4);
    float den0 = 0.f, den1 = 0.f, den2 = 0.f, den3 = 0.f;
    float num0 = 0.f, num1 = 0.f, num2 = 0.f, num3 = 0.f;
    if (half == 0) {  // self loop on lower half only
        const float4 a4 = *(const float4*)(als + (size_t)d * 4);
        den0 = expf(lrelu(a4.x + ad4.x));
        den1 = expf(lrelu(a4.y + ad4.y));
        den2 = expf(lrelu(a4.z + ad4.z));
        den3 = expf(lrelu(a4.w + ad4.w));
        const float* p = xh2 + (size_t)d * 128 + c;
        num0 = den0 * p[0];  num1 = den1 * p[32];
        num2 = den2 * p[64]; num3 = den3 * p[96];
    }
    const int start = row[d], end = row[d + 1];
    for (int i = start; i < end; i += 2) {
        const int my = i + half;
        const bool v = my < end;
        const int s = v ? esrc[my] : d;
        const float4 a4 = *(const float4*)(als + (size_t)s * 4);
        const float* p = xh2 + (size_t)s * 128 + c;
        const float x0 = p[0], x1 = p[32], x2 = p[64], x3 = p[96];
        float e0 = expf(lrelu(a4.x + ad4.x));
        float e1 = expf(lrelu(a4.y + ad4.y));
        float e2 = expf(lrelu(a4.z + ad4.z));
        float e3 = expf(lrelu(a4.w + ad4.w));
        if (!v) { e0 = e1 = e2 = e3 = 0.f; }
        den0 += e0; den1 += e1; den2 += e2; den3 += e3;
        num0 += e0 * x0; num1 += e1 * x1; num2 += e2 * x2; num3 += e3 * x3;
    }
    num0 += __shfl_xor(num0, 32); num1 += __shfl_xor(num1, 32);
    num2 += __shfl_xor(num2, 32); num3 += __shfl_xor(num3, 32);
    den0 += __shfl_xor(den0, 32); den1 += __shfl_xor(den1, 32);
    den2 += __shfl_xor(den2, 32); den3 += __shfl_xor(den3, 32);
    if (half == 0)
        agg2[(size_t)d * HID2 + c] =
            0.25f * (num0 / den0 + num1 / den1 + num2 / den2 + num3 / den3);
}

// ---------------- K8: final projections ----------------
#define NPB3 4
__global__ void k_final(const float* __restrict__ agg2, const float* __restrict__ b2,
                        const float* __restrict__ Wmu, const float* __restrict__ bmu,
                        const float* __restrict__ Wlv, const float* __restrict__ blv,
                        float* __restrict__ out) {
    __shared__ float hs[NPB3][HID2];
    const int tid = threadIdx.x;              // 256
    const int n0  = blockIdx.x * NPB3;
    if (tid < NPB3 * HID2) {
        int ni = tid >> 5, ci = tid & 31;
        float v = agg2[(size_t)(n0 + ni) * HID2 + ci] + b2[ci];
        hs[ni][ci] = v > 0.f ? v : 0.f;
    }
    __syncthreads();
    const int ni = tid >> 6;                  // 4 nodes per block
    const int which = (tid >> 5) & 1;         // 0 = mu, 1 = logvar
    const int l = tid & 31;
    const float* W = which ? Wlv : Wmu;
    const float* b = which ? blv : bmu;
    float acc = b[l];
#pragma unroll
    for (int c = 0; c < HID2; c++) acc += hs[ni][c] * W[c * LATENT + l];
    const int n = n0 + ni;
    out[(size_t)which * N_NODES * LATENT + (size_t)n * LATENT + l] = acc;
}

extern "C" void kernel_launch(void* const* d_in, const int* in_sizes, int n_in,
                              void* d_out, int out_size, void* d_ws, size_t ws_size,
                              hipStream_t stream) {
    const float* x    = (const float*)d_in[0];
    const int*   ei   = (const int*)d_in[1];
    const float* W1   = (const float*)d_in[2];
    const float* as1  = (const float*)d_in[3];
    const float* ad1  = (const float*)d_in[4];
    const float* b1   = (const float*)d_in[5];
    const float* W2   = (const float*)d_in[6];
    const float* as2  = (const float*)d_in[7];
    const float* ad2  = (const float*)d_in[8];
    const float* b2   = (const float*)d_in[9];
    const float* Wmu  = (const float*)d_in[10];
    const float* bmu  = (const float*)d_in[11];
    const float* Wlv  = (const float*)d_in[12];
    const float* blv  = (const float*)d_in[13];
    float* out = (float*)d_out;
    float* ws  = (float*)d_ws;

    float* xh1  = ws + OFF_XH1;
    float* als1 = ws + OFF_ALS1;
    float* ald1 = ws + OFF_ALD1;
    float* agg1 = ws + OFF_AGG1;
    float* xh2  = ws + OFF_XH2;
    float* als2 = ws + OFF_ALS2;
    float* ald2 = ws + OFF_ALD2;
    float* agg2 = ws + OFF_AGG2;
    int* deg  = (int*)(ws + OFF_DEG);   // also scatter cursor
    int* rowp = (int*)(ws + OFF_ROW);
    int* bsum = (int*)(ws + OFF_BSUM);
    int* esrc = (int*)(ws + OFF_ESRC);

    hipMemsetAsync(deg, 0, N_NODES * sizeof(int), stream);

    k_gemm1<<<N_NODES / NPB1, 256, 0, stream>>>(x, W1, as1, ad1, xh1, als1, ald1);

    // CSR build (dst-major)
    k_hist<<<(N_EDGES + 255) / 256, 256, 0, stream>>>(ei, deg);
    k_scan_part<<<NB_SCAN, 256, 0, stream>>>(deg, rowp, bsum);
    k_scan_block<<<1, 256, 0, stream>>>(bsum);
    k_scan_add<<<NB_SCAN, 256, 0, stream>>>(rowp, bsum, deg /*cursor*/);
    k_scatter<<<(N_EDGES + 255) / 256, 256, 0, stream>>>(ei, deg /*cursor*/, esrc);

    k_agg1_csr<<<(N_NODES + 3) / 4, 256, 0, stream>>>(rowp, esrc, als1, ald1, xh1, agg1);

    k_gemm2<<<N_NODES / NPB2, 128, 0, stream>>>(agg1, b1, W2, as2, ad2, xh2, als2, ald2);

    k_agg2_csr<<<(N_NODES + 3) / 4, 256, 0, stream>>>(rowp, esrc, als2, ald2, xh2, agg2);

    k_final<<<N_NODES / NPB3, 256, 0, stream>>>(agg2, b2, Wmu, bmu, Wlv, blv, out);
}

// Round 3
// 423.339 us; speedup vs baseline: 1.3079x; 1.0415x over previous
//
#include <hip/hip_runtime.h>

#define N_NODES 50000
#define N_EDGES 800000
#define IN_DIM  128
#define HID     64
#define HID2    32
#define HEADS   4
#define LATENT  32
#define NEG_SLOPE 0.2f

// ---------------- workspace layout (float offsets) ----------------
#define OFF_XH1   ((size_t)0)            // 12,800,000
#define OFF_XH2   ((size_t)0)            //  6,400,000 (overlay, xh1 dead)
#define OFF_AGG2  ((size_t)6400000)      //  1,600,000
#define OFF_ALS2  ((size_t)8000000)      //    200,000
#define OFF_ALD2  ((size_t)8200000)      //    200,000
#define OFF_AGG1  ((size_t)12800000)     //  3,200,000
#define OFF_ALS1  ((size_t)16000000)     //    200,000
#define OFF_ALD1  ((size_t)16200000)     //    200,000
// CSR (ints, stored in float slots)
#define OFF_DEG   ((size_t)16400000)     //     50,000  (reused as scatter cursor)
#define OFF_ROW   ((size_t)16450000)     //     50,001
#define OFF_BSUM  ((size_t)16500004)     //        256
#define OFF_ESRC  ((size_t)16500260)     //    800,000
// total 17,300,260 floats = 69.2 MB

#define NB_SCAN ((N_NODES + 255) / 256)  // 196

__device__ __forceinline__ float lrelu(float v) {
    return v > 0.f ? v : NEG_SLOPE * v;
}

// ---------------- K1: xh1 = x @ W1 ; als1/ald1 ----------------
#define NPB1 8
__global__ void k_gemm1(const float* __restrict__ x, const float* __restrict__ W1,
                        const float* __restrict__ as1, const float* __restrict__ ad1,
                        float* __restrict__ xh1, float* __restrict__ als,
                        float* __restrict__ ald) {
    __shared__ float xs[NPB1][IN_DIM];
    const int tid = threadIdx.x;              // 256
    const int n0  = blockIdx.x * NPB1;
    for (int i = tid; i < NPB1 * IN_DIM; i += 256) {
        int ni = i >> 7, ci = i & 127;
        xs[ni][ci] = x[(size_t)(n0 + ni) * IN_DIM + ci];
    }
    __syncthreads();
    float acc[NPB1];
#pragma unroll
    for (int i = 0; i < NPB1; i++) acc[i] = 0.f;
    for (int k = 0; k < IN_DIM; k++) {
        float w = W1[k * (HEADS * HID) + tid];
#pragma unroll
        for (int i = 0; i < NPB1; i++) acc[i] += xs[i][k] * w;
    }
    const int h = tid >> 6, c = tid & 63;     // wave == one head
    const float asv = as1[h * HID + c], adv = ad1[h * HID + c];
#pragma unroll
    for (int i = 0; i < NPB1; i++) {
        const int n = n0 + i;
        xh1[(size_t)n * (HEADS * HID) + tid] = acc[i];
        float ps = acc[i] * asv, pd = acc[i] * adv;
        for (int off = 32; off; off >>= 1) {
            ps += __shfl_down(ps, off);
            pd += __shfl_down(pd, off);
        }
        if (c == 0) { als[n * HEADS + h] = ps; ald[n * HEADS + h] = pd; }
    }
}

// ---------------- CSR build ----------------
__global__ void k_hist(const int* __restrict__ ei, int* __restrict__ deg) {
    const int e = blockIdx.x * blockDim.x + threadIdx.x;
    if (e >= N_EDGES) return;
    atomicAdd(&deg[ei[N_EDGES + e]], 1);
}

__global__ void k_scan_part(const int* __restrict__ deg, int* __restrict__ row,
                            int* __restrict__ bsum) {
    __shared__ int sm[256];
    const int tid = threadIdx.x;
    const int i = blockIdx.x * 256 + tid;
    const int v = (i < N_NODES) ? deg[i] : 0;
    sm[tid] = v;
    __syncthreads();
    for (int off = 1; off < 256; off <<= 1) {
        int t = (tid >= off) ? sm[tid - off] : 0;
        __syncthreads();
        sm[tid] += t;
        __syncthreads();
    }
    if (i < N_NODES) row[i] = sm[tid] - v;      // within-block exclusive
    if (tid == 255) bsum[blockIdx.x] = sm[255];
}

__global__ void k_scan_block(int* __restrict__ bsum) {
    __shared__ int sm[256];
    const int tid = threadIdx.x;
    const int v = (tid < NB_SCAN) ? bsum[tid] : 0;
    sm[tid] = v;
    __syncthreads();
    for (int off = 1; off < 256; off <<= 1) {
        int t = (tid >= off) ? sm[tid - off] : 0;
        __syncthreads();
        sm[tid] += t;
        __syncthreads();
    }
    if (tid < NB_SCAN) bsum[tid] = sm[tid] - v; // exclusive block offsets
}

__global__ void k_scan_add(int* __restrict__ row, const int* __restrict__ bsum,
                           int* __restrict__ cur) {
    const int i = blockIdx.x * 256 + threadIdx.x;
    if (i == 0) row[N_NODES] = N_EDGES;
    if (i >= N_NODES) return;
    const int r = row[i] + bsum[blockIdx.x];
    row[i] = r;
    cur[i] = r;
}

__global__ void k_scatter(const int* __restrict__ ei, int* __restrict__ cur,
                          int* __restrict__ esrc) {
    const int e = blockIdx.x * blockDim.x + threadIdx.x;
    if (e >= N_EDGES) return;
    const int s = ei[e], d = ei[N_EDGES + e];
    const int pos = atomicAdd(&cur[d], 1);
    esrc[pos] = s;
}

// ---------------- K3: layer-1 aggregation. Wave per node, cooperative exp ----------------
// Chunk of 16 edges: lane l computes exp for (edge l>>2, head l&3) -> LDS,
// then all 64 lanes (lane = channel) sweep the chunk accumulating features.
__global__ void k_agg1_csr(const int* __restrict__ row, const int* __restrict__ esrc,
                           const float* __restrict__ als, const float* __restrict__ ald,
                           const float* __restrict__ xh1, float* __restrict__ agg1) {
    __shared__ float smc[4][64];
    __shared__ int   smi[4][16];
    const int w = threadIdx.x >> 6;
    const int d = blockIdx.x * 4 + w;
    const int c = threadIdx.x & 63;
    if (d >= N_NODES) return;
    float* smc_w = smc[w];
    int*   smi_w = smi[w];
    const int h = c & 3;
    const float4 ad4 = *(const float4*)(ald + (size_t)d * 4);
    const float adh = (h == 0) ? ad4.x : (h == 1) ? ad4.y : (h == 2) ? ad4.z : ad4.w;
    // self-loop exp (computed redundantly once per node)
    float ds0, ds1, ds2, ds3;
    {
        const float4 a4 = *(const float4*)(als + (size_t)d * 4);
        ds0 = expf(lrelu(a4.x + ad4.x));
        ds1 = expf(lrelu(a4.y + ad4.y));
        ds2 = expf(lrelu(a4.z + ad4.z));
        ds3 = expf(lrelu(a4.w + ad4.w));
    }
    float num0, num1, num2, num3;
    {
        const float* p = xh1 + (size_t)d * 256 + c;
        num0 = ds0 * p[0];   num1 = ds1 * p[64];
        num2 = ds2 * p[128]; num3 = ds3 * p[192];
    }
    float denp = 0.f;   // lane-local partial denominator for head h
    const int start = row[d], end = row[d + 1];
    for (int i0 = start; i0 < end; i0 += 16) {
        int m = end - i0; if (m > 16) m = 16;
        const int slot = c >> 2;
        float ev = 0.f; int s = d;
        if (slot < m) {
            s = esrc[i0 + slot];
            ev = expf(lrelu(als[s * 4 + h] + adh));
        }
        denp += ev;
        smc_w[c] = ev;
        if (h == 0) smi_w[slot] = s;
        for (int j = 0; j < m; j++) {
            const float4 cf = *(const float4*)&smc_w[j * 4];
            const int sj = smi_w[j];
            const float* p = xh1 + (size_t)sj * 256 + c;
            num0 += cf.x * p[0];   num1 += cf.y * p[64];
            num2 += cf.z * p[128]; num3 += cf.w * p[192];
        }
    }
    // reduce denp over the 16 lanes sharing head h (lane bits 2..5)
    denp += __shfl_xor(denp, 4);
    denp += __shfl_xor(denp, 8);
    denp += __shfl_xor(denp, 16);
    denp += __shfl_xor(denp, 32);
    // lanes 0..3 hold totals for heads 0..3; publish (+ self term)
    if (c < 4) {
        const float dsh = (c == 0) ? ds0 : (c == 1) ? ds1 : (c == 2) ? ds2 : ds3;
        smc_w[c] = denp + dsh;
    }
    const float den0 = smc_w[0], den1 = smc_w[1], den2 = smc_w[2], den3 = smc_w[3];
    agg1[(size_t)d * HID + c] =
        0.25f * (num0 / den0 + num1 / den1 + num2 / den2 + num3 / den3);
}

// ---------------- K5: h1 = relu(agg1+b1); xh2 = h1 @ W2 ; als2/ald2 ----------------
#define NPB2 8
__global__ void k_gemm2(const float* __restrict__ agg1, const float* __restrict__ b1,
                        const float* __restrict__ W2, const float* __restrict__ as2,
                        const float* __restrict__ ad2, float* __restrict__ xh2,
                        float* __restrict__ als, float* __restrict__ ald) {
    __shared__ float hs[NPB2][HID];
    const int tid = threadIdx.x;              // 128
    const int n0  = blockIdx.x * NPB2;
    for (int i = tid; i < NPB2 * HID; i += 128) {
        int ni = i >> 6, ci = i & 63;
        float v = agg1[(size_t)(n0 + ni) * HID + ci] + b1[ci];
        hs[ni][ci] = v > 0.f ? v : 0.f;
    }
    __syncthreads();
    float acc[NPB2];
#pragma unroll
    for (int i = 0; i < NPB2; i++) acc[i] = 0.f;
    for (int k = 0; k < HID; k++) {
        float w = W2[k * (HEADS * HID2) + tid];
#pragma unroll
        for (int i = 0; i < NPB2; i++) acc[i] += hs[i][k] * w;
    }
    const int h = tid >> 5, c = tid & 31;     // 32-lane group == one head
    const float asv = as2[h * HID2 + c], adv = ad2[h * HID2 + c];
#pragma unroll
    for (int i = 0; i < NPB2; i++) {
        const int n = n0 + i;
        xh2[(size_t)n * (HEADS * HID2) + tid] = acc[i];
        float ps = acc[i] * asv, pd = acc[i] * adv;
        for (int off = 16; off; off >>= 1) {
            ps += __shfl_down(ps, off, 32);
            pd += __shfl_down(pd, off, 32);
        }
        if (c == 0) { als[n * HEADS + h] = ps; ald[n * HEADS + h] = pd; }
    }
}

// ---------------- K7: layer-2 aggregation. Wave per node, cooperative exp,
//                       half-wave channel split (2 edges in flight) ----------------
__global__ void k_agg2_csr(const int* __restrict__ row, const int* __restrict__ esrc,
                           const float* __restrict__ als, const float* __restrict__ ald,
                           const float* __restrict__ xh2, float* __restrict__ agg2) {
    __shared__ float smc[4][64];
    __shared__ int   smi[4][16];
    const int w = threadIdx.x >> 6;
    const int d = blockIdx.x * 4 + w;
    const int lane = threadIdx.x & 63;
    const int c2 = lane & 31, half = lane >> 5;
    if (d >= N_NODES) return;
    float* smc_w = smc[w];
    int*   smi_w = smi[w];
    const int h = lane & 3;
    const float4 ad4 = *(const float4*)(ald + (size_t)d * 4);
    const float adh = (h == 0) ? ad4.x : (h == 1) ? ad4.y : (h == 2) ? ad4.z : ad4.w;
    float ds0, ds1, ds2, ds3;
    {
        const float4 a4 = *(const float4*)(als + (size_t)d * 4);
        ds0 = expf(lrelu(a4.x + ad4.x));
        ds1 = expf(lrelu(a4.y + ad4.y));
        ds2 = expf(lrelu(a4.z + ad4.z));
        ds3 = expf(lrelu(a4.w + ad4.w));
    }
    float num0 = 0.f, num1 = 0.f, num2 = 0.f, num3 = 0.f;
    if (half == 0) {   // self-loop counted once
        const float* p = xh2 + (size_t)d * 128 + c2;
        num0 = ds0 * p[0];  num1 = ds1 * p[32];
        num2 = ds2 * p[64]; num3 = ds3 * p[96];
    }
    float denp = 0.f;
    const int start = row[d], end = row[d + 1];
    for (int i0 = start; i0 < end; i0 += 16) {
        int m = end - i0; if (m > 16) m = 16;
        const int slot = lane >> 2;
        float ev = 0.f; int s = d;
        if (slot < m) {
            s = esrc[i0 + slot];
            ev = expf(lrelu(als[s * 4 + h] + adh));
        }
        denp += ev;
        smc_w[lane] = ev;
        if (h == 0) smi_w[slot] = s;
        for (int j = half; j < m; j += 2) {
            const float4 cf = *(const float4*)&smc_w[j * 4];
            const int sj = smi_w[j];
            const float* p = xh2 + (size_t)sj * 128 + c2;
            num0 += cf.x * p[0];  num1 += cf.y * p[32];
            num2 += cf.z * p[64]; num3 += cf.w * p[96];
        }
    }
    num0 += __shfl_xor(num0, 32); num1 += __shfl_xor(num1, 32);
    num2 += __shfl_xor(num2, 32); num3 += __shfl_xor(num3, 32);
    denp += __shfl_xor(denp, 4);
    denp += __shfl_xor(denp, 8);
    denp += __shfl_xor(denp, 16);
    denp += __shfl_xor(denp, 32);
    if (lane < 4) {
        const float dsh = (lane == 0) ? ds0 : (lane == 1) ? ds1 : (lane == 2) ? ds2 : ds3;
        smc_w[lane] = denp + dsh;
    }
    const float den0 = smc_w[0], den1 = smc_w[1], den2 = smc_w[2], den3 = smc_w[3];
    if (half == 0)
        agg2[(size_t)d * HID2 + c2] =
            0.25f * (num0 / den0 + num1 / den1 + num2 / den2 + num3 / den3);
}

// ---------------- K8: final projections ----------------
#define NPB3 4
__global__ void k_final(const float* __restrict__ agg2, const float* __restrict__ b2,
                        const float* __restrict__ Wmu, const float* __restrict__ bmu,
                        const float* __restrict__ Wlv, const float* __restrict__ blv,
                        float* __restrict__ out) {
    __shared__ float hs[NPB3][HID2];
    const int tid = threadIdx.x;              // 256
    const int n0  = blockIdx.x * NPB3;
    if (tid < NPB3 * HID2) {
        int ni = tid >> 5, ci = tid & 31;
        float v = agg2[(size_t)(n0 + ni) * HID2 + ci] + b2[ci];
        hs[ni][ci] = v > 0.f ? v : 0.f;
    }
    __syncthreads();
    const int ni = tid >> 6;                  // 4 nodes per block
    const int which = (tid >> 5) & 1;         // 0 = mu, 1 = logvar
    const int l = tid & 31;
    const float* W = which ? Wlv : Wmu;
    const float* b = which ? blv : bmu;
    float acc = b[l];
#pragma unroll
    for (int c = 0; c < HID2; c++) acc += hs[ni][c] * W[c * LATENT + l];
    const int n = n0 + ni;
    out[(size_t)which * N_NODES * LATENT + (size_t)n * LATENT + l] = acc;
}

extern "C" void kernel_launch(void* const* d_in, const int* in_sizes, int n_in,
                              void* d_out, int out_size, void* d_ws, size_t ws_size,
                              hipStream_t stream) {
    const float* x    = (const float*)d_in[0];
    const int*   ei   = (const int*)d_in[1];
    const float* W1   = (const float*)d_in[2];
    const float* as1  = (const float*)d_in[3];
    const float* ad1  = (const float*)d_in[4];
    const float* b1   = (const float*)d_in[5];
    const float* W2   = (const float*)d_in[6];
    const float* as2  = (const float*)d_in[7];
    const float* ad2  = (const float*)d_in[8];
    const float* b2   = (const float*)d_in[9];
    const float* Wmu  = (const float*)d_in[10];
    const float* bmu  = (const float*)d_in[11];
    const float* Wlv  = (const float*)d_in[12];
    const float* blv  = (const float*)d_in[13];
    float* out = (float*)d_out;
    float* ws  = (float*)d_ws;

    float* xh1  = ws + OFF_XH1;
    float* als1 = ws + OFF_ALS1;
    float* ald1 = ws + OFF_ALD1;
    float* agg1 = ws + OFF_AGG1;
    float* xh2  = ws + OFF_XH2;
    float* als2 = ws + OFF_ALS2;
    float* ald2 = ws + OFF_ALD2;
    float* agg2 = ws + OFF_AGG2;
    int* deg  = (int*)(ws + OFF_DEG);   // also scatter cursor
    int* rowp = (int*)(ws + OFF_ROW);
    int* bsum = (int*)(ws + OFF_BSUM);
    int* esrc = (int*)(ws + OFF_ESRC);

    hipMemsetAsync(deg, 0, N_NODES * sizeof(int), stream);

    k_gemm1<<<N_NODES / NPB1, 256, 0, stream>>>(x, W1, as1, ad1, xh1, als1, ald1);

    // CSR build (dst-major)
    k_hist<<<(N_EDGES + 255) / 256, 256, 0, stream>>>(ei, deg);
    k_scan_part<<<NB_SCAN, 256, 0, stream>>>(deg, rowp, bsum);
    k_scan_block<<<1, 256, 0, stream>>>(bsum);
    k_scan_add<<<NB_SCAN, 256, 0, stream>>>(rowp, bsum, deg /*cursor*/);
    k_scatter<<<(N_EDGES + 255) / 256, 256, 0, stream>>>(ei, deg /*cursor*/, esrc);

    k_agg1_csr<<<(N_NODES + 3) / 4, 256, 0, stream>>>(rowp, esrc, als1, ald1, xh1, agg1);

    k_gemm2<<<N_NODES / NPB2, 128, 0, stream>>>(agg1, b1, W2, as2, ad2, xh2, als2, ald2);

    k_agg2_csr<<<(N_NODES + 3) / 4, 256, 0, stream>>>(rowp, esrc, als2, ald2, xh2, agg2);

    k_final<<<N_NODES / NPB3, 256, 0, stream>>>(agg2, b2, Wmu, bmu, Wlv, blv, out);
}

// Round 4
// 373.084 us; speedup vs baseline: 1.4841x; 1.1347x over previous
//
#include <hip/hip_runtime.h>
#include <hip/hip_fp16.h>

#define N_NODES 50000
#define N_EDGES 800000
#define IN_DIM  128
#define HID     64
#define HID2    32
#define HEADS   4
#define LATENT  32
#define NEG_SLOPE 0.2f

// ---------------- workspace layout (float offsets) ----------------
// xh1h: 12.8M halves = 6.4M float slots at 0. xh2h (3.2M float slots) overlays it.
#define OFF_XH1H  ((size_t)0)            //  6,400,000 (half storage)
#define OFF_XH2H  ((size_t)0)            //  3,200,000 (overlay, xh1 dead)
#define OFF_AGG2  ((size_t)6400000)      //  1,600,000
#define OFF_ALS2  ((size_t)8000000)      //    200,000
#define OFF_ALD2  ((size_t)8200000)      //    200,000
#define OFF_AGG1  ((size_t)8400000)      //  3,200,000
#define OFF_ALS1  ((size_t)11600000)     //    200,000
#define OFF_ALD1  ((size_t)11800000)     //    200,000
// CSR (ints in float slots)
#define OFF_DEG   ((size_t)12000000)     //     50,000 (reused as scatter cursor)
#define OFF_ROW   ((size_t)12050000)     //     50,001
#define OFF_BSUM  ((size_t)12100004)     //        256
#define OFF_ESRC  ((size_t)12100260)     //    800,000
// total 12,900,260 floats = 51.6 MB

#define NB_SCAN ((N_NODES + 255) / 256)  // 196

__device__ __forceinline__ float lrelu(float v) {
    return v > 0.f ? v : NEG_SLOPE * v;
}

// ---------------- K1: xh1h = half(x @ W1) ; als1/ald1 (fp32) ----------------
#define NPB1 8
__global__ void k_gemm1(const float* __restrict__ x, const float* __restrict__ W1,
                        const float* __restrict__ as1, const float* __restrict__ ad1,
                        __half* __restrict__ xh1, float* __restrict__ als,
                        float* __restrict__ ald) {
    __shared__ float xs[NPB1][IN_DIM];
    const int tid = threadIdx.x;              // 256
    const int n0  = blockIdx.x * NPB1;
    for (int i = tid; i < NPB1 * IN_DIM; i += 256) {
        int ni = i >> 7, ci = i & 127;
        xs[ni][ci] = x[(size_t)(n0 + ni) * IN_DIM + ci];
    }
    __syncthreads();
    float acc[NPB1];
#pragma unroll
    for (int i = 0; i < NPB1; i++) acc[i] = 0.f;
    for (int k = 0; k < IN_DIM; k++) {
        float w = W1[k * (HEADS * HID) + tid];
#pragma unroll
        for (int i = 0; i < NPB1; i++) acc[i] += xs[i][k] * w;
    }
    const int h = tid >> 6, c = tid & 63;     // wave == one head
    const float asv = as1[h * HID + c], adv = ad1[h * HID + c];
#pragma unroll
    for (int i = 0; i < NPB1; i++) {
        const int n = n0 + i;
        xh1[(size_t)n * (HEADS * HID) + tid] = __float2half(acc[i]);
        float ps = acc[i] * asv, pd = acc[i] * adv;
        for (int off = 32; off; off >>= 1) {
            ps += __shfl_down(ps, off);
            pd += __shfl_down(pd, off);
        }
        if (c == 0) { als[n * HEADS + h] = ps; ald[n * HEADS + h] = pd; }
    }
}

// ---------------- CSR build ----------------
__global__ void k_hist(const int* __restrict__ ei, int* __restrict__ deg) {
    const int e = blockIdx.x * blockDim.x + threadIdx.x;
    if (e >= N_EDGES) return;
    atomicAdd(&deg[ei[N_EDGES + e]], 1);
}

__global__ void k_scan_part(const int* __restrict__ deg, int* __restrict__ row,
                            int* __restrict__ bsum) {
    __shared__ int sm[256];
    const int tid = threadIdx.x;
    const int i = blockIdx.x * 256 + tid;
    const int v = (i < N_NODES) ? deg[i] : 0;
    sm[tid] = v;
    __syncthreads();
    for (int off = 1; off < 256; off <<= 1) {
        int t = (tid >= off) ? sm[tid - off] : 0;
        __syncthreads();
        sm[tid] += t;
        __syncthreads();
    }
    if (i < N_NODES) row[i] = sm[tid] - v;      // within-block exclusive
    if (tid == 255) bsum[blockIdx.x] = sm[255];
}

__global__ void k_scan_block(int* __restrict__ bsum) {
    __shared__ int sm[256];
    const int tid = threadIdx.x;
    const int v = (tid < NB_SCAN) ? bsum[tid] : 0;
    sm[tid] = v;
    __syncthreads();
    for (int off = 1; off < 256; off <<= 1) {
        int t = (tid >= off) ? sm[tid - off] : 0;
        __syncthreads();
        sm[tid] += t;
        __syncthreads();
    }
    if (tid < NB_SCAN) bsum[tid] = sm[tid] - v; // exclusive block offsets
}

__global__ void k_scan_add(int* __restrict__ row, const int* __restrict__ bsum,
                           int* __restrict__ cur) {
    const int i = blockIdx.x * 256 + threadIdx.x;
    if (i == 0) row[N_NODES] = N_EDGES;
    if (i >= N_NODES) return;
    const int r = row[i] + bsum[blockIdx.x];
    row[i] = r;
    cur[i] = r;
}

__global__ void k_scatter(const int* __restrict__ ei, int* __restrict__ cur,
                          int* __restrict__ esrc) {
    const int e = blockIdx.x * blockDim.x + threadIdx.x;
    if (e >= N_EDGES) return;
    const int s = ei[e], d = ei[N_EDGES + e];
    const int pos = atomicAdd(&cur[d], 1);
    esrc[pos] = s;
}

// ---------------- K3: layer-1 aggregation. Wave per node, all-shuffle ----------------
// Edge t in [0, deg+1): t==0 is the self loop. Chunks of 16 edges:
// exp phase: lane l -> edge (l>>2), head (l&3).
// sweep: lane l owns 4 adjacent channels of head (l>>4); 1 dwordx2 load/edge.
__global__ void k_agg1_h(const int* __restrict__ row, const int* __restrict__ esrc,
                         const float* __restrict__ als, const float* __restrict__ ald,
                         const __half* __restrict__ xh1, float* __restrict__ agg1) {
    const int d = blockIdx.x * 4 + (threadIdx.x >> 6);
    const int lane = threadIdx.x & 63;
    if (d >= N_NODES) return;
    const int hq = lane >> 4;       // head this lane accumulates
    const int he = lane & 3;        // head this lane exponentiates
    const float adh = ald[d * 4 + he];
    const int start = row[d];
    const int total = row[d + 1] - start + 1;   // + self loop
    float acc0 = 0.f, acc1 = 0.f, acc2 = 0.f, acc3 = 0.f;
    float denp = 0.f;
    for (int t0 = 0; t0 < total; t0 += 16) {
        int m = total - t0; if (m > 16) m = 16;
        const int slot = lane >> 2;
        float ev = 0.f; int s = d;
        if (slot < m) {
            const int t = t0 + slot;
            if (t > 0) s = esrc[start + t - 1];
            ev = expf(lrelu(als[s * 4 + he] + adh));
        }
        denp += ev;
        for (int j = 0; j < m; j++) {
            const float cf = __shfl(ev, j * 4 + hq);
            const int sj   = __shfl(s, j * 4);
            const float2 raw = *(const float2*)((const char*)xh1 +
                                 ((size_t)sj << 9) + (lane << 3));
            const __half2 h01 = *(const __half2*)&raw.x;
            const __half2 h23 = *(const __half2*)&raw.y;
            const float2 x01 = __half22float2(h01);
            const float2 x23 = __half22float2(h23);
            acc0 += cf * x01.x; acc1 += cf * x01.y;
            acc2 += cf * x23.x; acc3 += cf * x23.y;
        }
    }
    // reduce denp over the 16 lanes sharing head he
    denp += __shfl_xor(denp, 4);
    denp += __shfl_xor(denp, 8);
    denp += __shfl_xor(denp, 16);
    denp += __shfl_xor(denp, 32);
    const float deninv = 1.f / __shfl(denp, hq);   // lane hq holds head hq's den
    acc0 *= deninv; acc1 *= deninv; acc2 *= deninv; acc3 *= deninv;
    // sum over heads (lanes differing in bits 4,5)
    acc0 += __shfl_xor(acc0, 16); acc0 += __shfl_xor(acc0, 32);
    acc1 += __shfl_xor(acc1, 16); acc1 += __shfl_xor(acc1, 32);
    acc2 += __shfl_xor(acc2, 16); acc2 += __shfl_xor(acc2, 32);
    acc3 += __shfl_xor(acc3, 16); acc3 += __shfl_xor(acc3, 32);
    if (lane < 16) {
        float4 st = { 0.25f * acc0, 0.25f * acc1, 0.25f * acc2, 0.25f * acc3 };
        *(float4*)(agg1 + (size_t)d * HID + lane * 4) = st;
    }
}

// ---------------- K5: h1 = relu(agg1+b1); xh2h = half(h1 @ W2) ; als2/ald2 ----------------
#define NPB2 8
__global__ void k_gemm2(const float* __restrict__ agg1, const float* __restrict__ b1,
                        const float* __restrict__ W2, const float* __restrict__ as2,
                        const float* __restrict__ ad2, __half* __restrict__ xh2,
                        float* __restrict__ als, float* __restrict__ ald) {
    __shared__ float hs[NPB2][HID];
    const int tid = threadIdx.x;              // 128
    const int n0  = blockIdx.x * NPB2;
    for (int i = tid; i < NPB2 * HID; i += 128) {
        int ni = i >> 6, ci = i & 63;
        float v = agg1[(size_t)(n0 + ni) * HID + ci] + b1[ci];
        hs[ni][ci] = v > 0.f ? v : 0.f;
    }
    __syncthreads();
    float acc[NPB2];
#pragma unroll
    for (int i = 0; i < NPB2; i++) acc[i] = 0.f;
    for (int k = 0; k < HID; k++) {
        float w = W2[k * (HEADS * HID2) + tid];
#pragma unroll
        for (int i = 0; i < NPB2; i++) acc[i] += hs[i][k] * w;
    }
    const int h = tid >> 5, c = tid & 31;     // 32-lane group == one head
    const float asv = as2[h * HID2 + c], adv = ad2[h * HID2 + c];
#pragma unroll
    for (int i = 0; i < NPB2; i++) {
        const int n = n0 + i;
        xh2[(size_t)n * (HEADS * HID2) + tid] = __float2half(acc[i]);
        float ps = acc[i] * asv, pd = acc[i] * adv;
        for (int off = 16; off; off >>= 1) {
            ps += __shfl_down(ps, off, 32);
            pd += __shfl_down(pd, off, 32);
        }
        if (c == 0) { als[n * HEADS + h] = ps; ald[n * HEADS + h] = pd; }
    }
}

// ---------------- K7: layer-2 aggregation. Wave per node, all-shuffle ----------------
// Lane l owns 2 adjacent channels of head (l>>4); 1 dword load/edge.
__global__ void k_agg2_h(const int* __restrict__ row, const int* __restrict__ esrc,
                         const float* __restrict__ als, const float* __restrict__ ald,
                         const __half* __restrict__ xh2, float* __restrict__ agg2) {
    const int d = blockIdx.x * 4 + (threadIdx.x >> 6);
    const int lane = threadIdx.x & 63;
    if (d >= N_NODES) return;
    const int hq = lane >> 4;
    const int he = lane & 3;
    const float adh = ald[d * 4 + he];
    const int start = row[d];
    const int total = row[d + 1] - start + 1;   // + self loop
    float acc0 = 0.f, acc1 = 0.f;
    float denp = 0.f;
    for (int t0 = 0; t0 < total; t0 += 16) {
        int m = total - t0; if (m > 16) m = 16;
        const int slot = lane >> 2;
        float ev = 0.f; int s = d;
        if (slot < m) {
            const int t = t0 + slot;
            if (t > 0) s = esrc[start + t - 1];
            ev = expf(lrelu(als[s * 4 + he] + adh));
        }
        denp += ev;
        for (int j = 0; j < m; j++) {
            const float cf = __shfl(ev, j * 4 + hq);
            const int sj   = __shfl(s, j * 4);
            const __half2 hv = *(const __half2*)((const char*)xh2 +
                                ((size_t)sj << 8) + (lane << 2));
            const float2 xv = __half22float2(hv);
            acc0 += cf * xv.x; acc1 += cf * xv.y;
        }
    }
    denp += __shfl_xor(denp, 4);
    denp += __shfl_xor(denp, 8);
    denp += __shfl_xor(denp, 16);
    denp += __shfl_xor(denp, 32);
    const float deninv = 1.f / __shfl(denp, hq);
    acc0 *= deninv; acc1 *= deninv;
    acc0 += __shfl_xor(acc0, 16); acc0 += __shfl_xor(acc0, 32);
    acc1 += __shfl_xor(acc1, 16); acc1 += __shfl_xor(acc1, 32);
    if (lane < 16) {
        float2 st = { 0.25f * acc0, 0.25f * acc1 };
        *(float2*)(agg2 + (size_t)d * HID2 + lane * 2) = st;
    }
}

// ---------------- K8: final projections ----------------
#define NPB3 4
__global__ void k_final(const float* __restrict__ agg2, const float* __restrict__ b2,
                        const float* __restrict__ Wmu, const float* __restrict__ bmu,
                        const float* __restrict__ Wlv, const float* __restrict__ blv,
                        float* __restrict__ out) {
    __shared__ float hs[NPB3][HID2];
    const int tid = threadIdx.x;              // 256
    const int n0  = blockIdx.x * NPB3;
    if (tid < NPB3 * HID2) {
        int ni = tid >> 5, ci = tid & 31;
        float v = agg2[(size_t)(n0 + ni) * HID2 + ci] + b2[ci];
        hs[ni][ci] = v > 0.f ? v : 0.f;
    }
    __syncthreads();
    const int ni = tid >> 6;                  // 4 nodes per block
    const int which = (tid >> 5) & 1;         // 0 = mu, 1 = logvar
    const int l = tid & 31;
    const float* W = which ? Wlv : Wmu;
    const float* b = which ? blv : bmu;
    float acc = b[l];
#pragma unroll
    for (int c = 0; c < HID2; c++) acc += hs[ni][c] * W[c * LATENT + l];
    const int n = n0 + ni;
    out[(size_t)which * N_NODES * LATENT + (size_t)n * LATENT + l] = acc;
}

extern "C" void kernel_launch(void* const* d_in, const int* in_sizes, int n_in,
                              void* d_out, int out_size, void* d_ws, size_t ws_size,
                              hipStream_t stream) {
    const float* x    = (const float*)d_in[0];
    const int*   ei   = (const int*)d_in[1];
    const float* W1   = (const float*)d_in[2];
    const float* as1  = (const float*)d_in[3];
    const float* ad1  = (const float*)d_in[4];
    const float* b1   = (const float*)d_in[5];
    const float* W2   = (const float*)d_in[6];
    const float* as2  = (const float*)d_in[7];
    const float* ad2  = (const float*)d_in[8];
    const float* b2   = (const float*)d_in[9];
    const float* Wmu  = (const float*)d_in[10];
    const float* bmu  = (const float*)d_in[11];
    const float* Wlv  = (const float*)d_in[12];
    const float* blv  = (const float*)d_in[13];
    float* out = (float*)d_out;
    float* ws  = (float*)d_ws;

    __half* xh1h = (__half*)(ws + OFF_XH1H);
    __half* xh2h = (__half*)(ws + OFF_XH2H);
    float* als1 = ws + OFF_ALS1;
    float* ald1 = ws + OFF_ALD1;
    float* agg1 = ws + OFF_AGG1;
    float* als2 = ws + OFF_ALS2;
    float* ald2 = ws + OFF_ALD2;
    float* agg2 = ws + OFF_AGG2;
    int* deg  = (int*)(ws + OFF_DEG);   // also scatter cursor
    int* rowp = (int*)(ws + OFF_ROW);
    int* bsum = (int*)(ws + OFF_BSUM);
    int* esrc = (int*)(ws + OFF_ESRC);

    hipMemsetAsync(deg, 0, N_NODES * sizeof(int), stream);

    k_gemm1<<<N_NODES / NPB1, 256, 0, stream>>>(x, W1, as1, ad1, xh1h, als1, ald1);

    // CSR build (dst-major)
    k_hist<<<(N_EDGES + 255) / 256, 256, 0, stream>>>(ei, deg);
    k_scan_part<<<NB_SCAN, 256, 0, stream>>>(deg, rowp, bsum);
    k_scan_block<<<1, 256, 0, stream>>>(bsum);
    k_scan_add<<<NB_SCAN, 256, 0, stream>>>(rowp, bsum, deg /*cursor*/);
    k_scatter<<<(N_EDGES + 255) / 256, 256, 0, stream>>>(ei, deg /*cursor*/, esrc);

    k_agg1_h<<<(N_NODES + 3) / 4, 256, 0, stream>>>(rowp, esrc, als1, ald1, xh1h, agg1);

    k_gemm2<<<N_NODES / NPB2, 128, 0, stream>>>(agg1, b1, W2, as2, ad2, xh2h, als2, ald2);

    k_agg2_h<<<(N_NODES + 3) / 4, 256, 0, stream>>>(rowp, esrc, als2, ald2, xh2h, agg2);

    k_final<<<N_NODES / NPB3, 256, 0, stream>>>(agg2, b2, Wmu, bmu, Wlv, blv, out);
}